// Round 1
// baseline (76.370 us; speedup 1.0000x reference)
//
#include <hip/hip_runtime.h>

// SoftRAMAttention — S=2048, B=64, H=8, K=12, N_POS=11
//
// addr[i,j,h] = addr_q[i,h] | addr_k[j,h] | addr_p[i-j,h]  (disjoint bit groups)
// votes[i,j]  = sum_h head_table_bit[h][addr]
// out[i,:]    = max_j<=i votes > 0 ? table_v[:, addr_v[argmax_row]] : 0

#define SS 2048
#define BB 64
#define HH 8
#define KK 12
#define NPOS 11
#define TBL 4096           // 1 << KK
#define TBLW (TBL / 32)    // 128 words per head

// ws int layout:
//   A   : [0,        S*H)       addr_q per (s,h)
//   AK  : [S*H,      2*S*H)     addr_k per (s,h)
//   P   : [2*S*H,    3*S*H)     addr_p per (d,h)
//   bits: [3*S*H,    3*S*H+H*TBLW)  packed head_table

__global__ __launch_bounds__(256) void precompute_kernel(
    const int* __restrict__ tokens,        // (S,B) values {0,1}
    const int* __restrict__ conn_heads,    // (H,K)
    const float* __restrict__ head_table,  // (H,4096) values {0.0,1.0}
    int* __restrict__ A, int* __restrict__ AK, int* __restrict__ P,
    unsigned int* __restrict__ bits)
{
    int gid = blockIdx.x * blockDim.x + threadIdx.x;
    if (gid < SS * HH) {
        int s = gid >> 3;
        int h = gid & 7;
        int aq = 0, ak = 0, ap = 0;
        #pragma unroll
        for (int k = 0; k < KK; ++k) {
            int c = conn_heads[h * KK + k];
            int sh = KK - 1 - k;
            if (c < BB) {
                aq |= (tokens[s * BB + c] & 1) << sh;
            } else if (c < 2 * BB) {
                ak |= (tokens[s * BB + (c - BB)] & 1) << sh;
            } else {
                int cp = c - 2 * BB;              // in [0, NPOS)
                ap |= ((s >> (NPOS - 1 - cp)) & 1) << sh;
            }
        }
        A[gid] = aq;
        AK[gid] = ak;
        P[gid] = ap;
    } else {
        int w = gid - SS * HH;
        if (w < HH * TBLW) {
            int h = w >> 7;
            int wi = w & (TBLW - 1);
            unsigned int bv = 0;
            #pragma unroll
            for (int b = 0; b < 32; ++b) {
                if (head_table[h * TBL + wi * 32 + b] > 0.5f) bv |= (1u << b);
            }
            bits[w] = bv;
        }
    }
}

__global__ __launch_bounds__(256) void vote_kernel(
    const int* __restrict__ A, const int* __restrict__ AK, const int* __restrict__ P,
    const unsigned int* __restrict__ bits_g,
    const int* __restrict__ tokens,     // (S,B)
    const int* __restrict__ conn_v,     // (B,K)
    const float* __restrict__ table_v,  // (B,4096)
    float* __restrict__ out)            // (S,B) fp32
{
    __shared__ unsigned int sbits[HH * TBLW];   // 4 KB
    __shared__ int sv[256];
    __shared__ int sj[256];

    const int tid = threadIdx.x;
    const int i = blockIdx.x;

    for (int t = tid; t < HH * TBLW; t += 256) sbits[t] = bits_g[t];
    __syncthreads();

    const int4 a0 = *(const int4*)(A + i * HH);
    const int4 a1 = *(const int4*)(A + i * HH + 4);

    int bv = -1;   // votes >= 0, so -1 marks "no column visited"
    int bj = 0;
    for (int j = tid; j <= i; j += 256) {
        const int4 k0 = *(const int4*)(AK + j * HH);
        const int4 k1 = *(const int4*)(AK + j * HH + 4);
        const int d = i - j;
        const int4 p0 = *(const int4*)(P + d * HH);
        const int4 p1 = *(const int4*)(P + d * HH + 4);
        int v = 0, a;
        a = a0.x | k0.x | p0.x; v += (sbits[(0 << 7) + (a >> 5)] >> (a & 31)) & 1;
        a = a0.y | k0.y | p0.y; v += (sbits[(1 << 7) + (a >> 5)] >> (a & 31)) & 1;
        a = a0.z | k0.z | p0.z; v += (sbits[(2 << 7) + (a >> 5)] >> (a & 31)) & 1;
        a = a0.w | k0.w | p0.w; v += (sbits[(3 << 7) + (a >> 5)] >> (a & 31)) & 1;
        a = a1.x | k1.x | p1.x; v += (sbits[(4 << 7) + (a >> 5)] >> (a & 31)) & 1;
        a = a1.y | k1.y | p1.y; v += (sbits[(5 << 7) + (a >> 5)] >> (a & 31)) & 1;
        a = a1.z | k1.z | p1.z; v += (sbits[(6 << 7) + (a >> 5)] >> (a & 31)) & 1;
        a = a1.w | k1.w | p1.w; v += (sbits[(7 << 7) + (a >> 5)] >> (a & 31)) & 1;
        // strictly-greater keeps the SMALLEST j at the max within this thread
        if (v > bv) { bv = v; bj = j; }
    }

    sv[tid] = bv;
    sj[tid] = bj;
    __syncthreads();
    // block reduce: max vote, tie -> smallest j (matches jnp.argmax first-occurrence)
    for (int off = 128; off > 0; off >>= 1) {
        if (tid < off) {
            int v2 = sv[tid + off], j2 = sj[tid + off];
            if (v2 > sv[tid] || (v2 == sv[tid] && j2 < sj[tid])) {
                sv[tid] = v2; sj[tid] = j2;
            }
        }
        __syncthreads();
    }
    const int maxv = sv[0];
    const int best = sj[0];

    if (tid < BB) {
        float o = 0.0f;
        if (maxv > 0) {
            int av = 0;
            #pragma unroll
            for (int k = 0; k < KK; ++k) {
                int c = conn_v[tid * KK + k];
                av |= (tokens[best * BB + c] & 1) << (KK - 1 - k);
            }
            o = table_v[tid * TBL + av];
        }
        out[i * BB + tid] = o;
    }
}

extern "C" void kernel_launch(void* const* d_in, const int* in_sizes, int n_in,
                              void* d_out, int out_size, void* d_ws, size_t ws_size,
                              hipStream_t stream) {
    const int*   tokens     = (const int*)d_in[0];
    const int*   conn_heads = (const int*)d_in[1];
    const float* head_table = (const float*)d_in[2];
    const int*   conn_v     = (const int*)d_in[3];
    const float* table_v    = (const float*)d_in[4];
    float* out = (float*)d_out;

    int* ws = (int*)d_ws;
    int* A  = ws;
    int* AK = ws + SS * HH;
    int* P  = ws + 2 * SS * HH;
    unsigned int* bits = (unsigned int*)(ws + 3 * SS * HH);

    const int total1 = SS * HH + HH * TBLW;   // 16384 + 1024
    precompute_kernel<<<(total1 + 255) / 256, 256, 0, stream>>>(
        tokens, conn_heads, head_table, A, AK, P, bits);
    vote_kernel<<<SS, 256, 0, stream>>>(
        A, AK, P, bits, tokens, conn_v, table_v, out);
}

// Round 2
// 73.584 us; speedup vs baseline: 1.0379x; 1.0379x over previous
//
#include <hip/hip_runtime.h>

// SoftRAMAttention — S=2048, B=64, H=8, K=12, N_POS=11
//
// addr[i,j,h] = addr_q[i,h] | addr_k[j,h] | addr_p[i-j,h]  (disjoint bit groups)
// votes[i,j]  = sum_h head_table_bit[h][addr]   (head_table is 0/1 -> bit-packed)
// out[i,:]    = max_{j<=i} votes > 0 ? table_v[:, addr_v[argmax]] : 0
//
// R1: pair rows (b, S-1-b) per block -> perfect balance, 1024 blocks;
//     shuffle-key reduction (key = (v<<12)|(4095-j), max == (max v, min j));
//     2 barriers per block instead of ~18.

#define SS 2048
#define BB 64
#define HH 8
#define KK 12
#define NPOS 11
#define TBL 4096           // 1 << KK
#define TBLW (TBL / 32)    // 128 words per head

__global__ __launch_bounds__(256) void precompute_kernel(
    const int* __restrict__ tokens,        // (S,B) values {0,1}
    const int* __restrict__ conn_heads,    // (H,K)
    const float* __restrict__ head_table,  // (H,4096) values {0.0,1.0}
    int* __restrict__ A, int* __restrict__ AK, int* __restrict__ P,
    unsigned int* __restrict__ bits)
{
    int gid = blockIdx.x * blockDim.x + threadIdx.x;
    if (gid < SS * HH) {
        int s = gid >> 3;
        int h = gid & 7;
        int aq = 0, ak = 0, ap = 0;
        #pragma unroll
        for (int k = 0; k < KK; ++k) {
            int c = conn_heads[h * KK + k];
            int sh = KK - 1 - k;
            if (c < BB) {
                aq |= (tokens[s * BB + c] & 1) << sh;
            } else if (c < 2 * BB) {
                ak |= (tokens[s * BB + (c - BB)] & 1) << sh;
            } else {
                int cp = c - 2 * BB;              // in [0, NPOS)
                ap |= ((s >> (NPOS - 1 - cp)) & 1) << sh;
            }
        }
        A[gid] = aq;
        AK[gid] = ak;
        P[gid] = ap;
    } else {
        int w = gid - SS * HH;
        if (w < HH * TBLW) {
            int h = w >> 7;
            int wi = w & (TBLW - 1);
            unsigned int bv = 0;
            #pragma unroll
            for (int b = 0; b < 32; ++b) {
                if (head_table[h * TBL + wi * 32 + b] > 0.5f) bv |= (1u << b);
            }
            bits[w] = bv;
        }
    }
}

__device__ __forceinline__ int votes8(const unsigned int* sbits,
                                      const int4& q0, const int4& q1,
                                      const int4& k0, const int4& k1,
                                      const int4& p0, const int4& p1)
{
    int v = 0, a;
    a = q0.x | k0.x | p0.x; v += (sbits[0 * TBLW + (a >> 5)] >> (a & 31)) & 1;
    a = q0.y | k0.y | p0.y; v += (sbits[1 * TBLW + (a >> 5)] >> (a & 31)) & 1;
    a = q0.z | k0.z | p0.z; v += (sbits[2 * TBLW + (a >> 5)] >> (a & 31)) & 1;
    a = q0.w | k0.w | p0.w; v += (sbits[3 * TBLW + (a >> 5)] >> (a & 31)) & 1;
    a = q1.x | k1.x | p1.x; v += (sbits[4 * TBLW + (a >> 5)] >> (a & 31)) & 1;
    a = q1.y | k1.y | p1.y; v += (sbits[5 * TBLW + (a >> 5)] >> (a & 31)) & 1;
    a = q1.z | k1.z | p1.z; v += (sbits[6 * TBLW + (a >> 5)] >> (a & 31)) & 1;
    a = q1.w | k1.w | p1.w; v += (sbits[7 * TBLW + (a >> 5)] >> (a & 31)) & 1;
    return v;
}

__global__ __launch_bounds__(256) void vote_kernel(
    const int* __restrict__ A, const int* __restrict__ AK, const int* __restrict__ P,
    const unsigned int* __restrict__ bits_g,
    const int* __restrict__ tokens,     // (S,B)
    const int* __restrict__ conn_v,     // (B,K)
    const float* __restrict__ table_v,  // (B,4096)
    float* __restrict__ out)            // (S,B) fp32
{
    __shared__ unsigned int sbits[HH * TBLW];   // 4 KB
    __shared__ unsigned int skey[2][4];

    const int tid = threadIdx.x;
    const int b = blockIdx.x;
    const int i0 = b;             // short row (i0 <= 1023)
    const int i1 = SS - 1 - b;    // long row  (i1 >= 1024)

    // stage packed tables: 256 threads x 16B = 4 KB exactly
    ((uint4*)sbits)[tid] = ((const uint4*)bits_g)[tid];
    __syncthreads();

    const int4 q00 = *(const int4*)(A + i0 * HH);
    const int4 q01 = *(const int4*)(A + i0 * HH + 4);
    const int4 q10 = *(const int4*)(A + i1 * HH);
    const int4 q11 = *(const int4*)(A + i1 * HH + 4);

    // key = (v << 12) | (4095 - j): max key == max v, tie -> smallest j.
    // key 0 == "nothing visited"; a visited column always has key >= 2048 > 0.
    unsigned int key0 = 0u, key1 = 0u;

    for (int j = tid; j <= i0; j += 256) {
        const int4 k0 = *(const int4*)(AK + j * HH);
        const int4 k1 = *(const int4*)(AK + j * HH + 4);
        const int d = i0 - j;
        const int4 p0 = *(const int4*)(P + d * HH);
        const int4 p1 = *(const int4*)(P + d * HH + 4);
        int v = votes8(sbits, q00, q01, k0, k1, p0, p1);
        unsigned int key = ((unsigned)v << 12) | (unsigned)(4095 - j);
        key0 = key0 > key ? key0 : key;
    }
    for (int j = tid; j <= i1; j += 256) {
        const int4 k0 = *(const int4*)(AK + j * HH);
        const int4 k1 = *(const int4*)(AK + j * HH + 4);
        const int d = i1 - j;
        const int4 p0 = *(const int4*)(P + d * HH);
        const int4 p1 = *(const int4*)(P + d * HH + 4);
        int v = votes8(sbits, q10, q11, k0, k1, p0, p1);
        unsigned int key = ((unsigned)v << 12) | (unsigned)(4095 - j);
        key1 = key1 > key ? key1 : key;
    }

    // 64-lane butterfly max for both rows (no barriers)
    #pragma unroll
    for (int off = 32; off > 0; off >>= 1) {
        unsigned int o0 = (unsigned int)__shfl_xor((int)key0, off, 64);
        unsigned int o1 = (unsigned int)__shfl_xor((int)key1, off, 64);
        key0 = key0 > o0 ? key0 : o0;
        key1 = key1 > o1 ? key1 : o1;
    }
    if ((tid & 63) == 0) {
        skey[0][tid >> 6] = key0;
        skey[1][tid >> 6] = key1;
    }
    __syncthreads();

    // threads 0..63 emit row i0, threads 64..127 emit row i1
    if (tid < 128) {
        const int r = tid >> 6;
        const int lane = tid & 63;
        unsigned int ka = skey[r][0] > skey[r][1] ? skey[r][0] : skey[r][1];
        unsigned int kb = skey[r][2] > skey[r][3] ? skey[r][2] : skey[r][3];
        unsigned int kf = ka > kb ? ka : kb;
        const int row = r ? i1 : i0;
        float o = 0.0f;
        if ((kf >> 12) > 0) {
            const int best = 4095 - (int)(kf & 4095u);
            int av = 0;
            #pragma unroll
            for (int k = 0; k < KK; ++k) {
                int c = conn_v[lane * KK + k];
                av |= (tokens[best * BB + c] & 1) << (KK - 1 - k);
            }
            o = table_v[lane * TBL + av];
        }
        out[row * BB + lane] = o;
    }
}

extern "C" void kernel_launch(void* const* d_in, const int* in_sizes, int n_in,
                              void* d_out, int out_size, void* d_ws, size_t ws_size,
                              hipStream_t stream) {
    const int*   tokens     = (const int*)d_in[0];
    const int*   conn_heads = (const int*)d_in[1];
    const float* head_table = (const float*)d_in[2];
    const int*   conn_v     = (const int*)d_in[3];
    const float* table_v    = (const float*)d_in[4];
    float* out = (float*)d_out;

    int* ws = (int*)d_ws;
    int* A  = ws;
    int* AK = ws + SS * HH;
    int* P  = ws + 2 * SS * HH;
    unsigned int* bits = (unsigned int*)(ws + 3 * SS * HH);

    const int total1 = SS * HH + HH * TBLW;   // 16384 + 1024
    precompute_kernel<<<(total1 + 255) / 256, 256, 0, stream>>>(
        tokens, conn_heads, head_table, A, AK, P, bits);
    vote_kernel<<<SS / 2, 256, 0, stream>>>(
        A, AK, P, bits, tokens, conn_v, table_v, out);
}

// Round 3
// 72.694 us; speedup vs baseline: 1.0506x; 1.0122x over previous
//
#include <hip/hip_runtime.h>

// SoftRAMAttention — S=2048, B=64, H=8, K=12, N_POS=11
//
// addr[i,j,h] = addr_q[i,h] | addr_k[j,h] | addr_p[i-j,h]  (disjoint bit groups)
// votes[i,j]  = sum_h head_table_bit[h][addr]   (head_table is 0/1 -> bit-packed)
// out[i,:]    = max_{j<=i} votes > 0 ? table_v[:, addr_v[argmax]] : 0
//
// R3: addresses packed 8 x ushort (uint4) -> packed ORs (4 for 8 heads),
//     halved load bytes; early-exit chunk scan on v==8 (answer is "first j
//     with v==8" whenever an 8 exists — Binomial(8,1/2) max).

#define SS 2048
#define BB 64
#define HH 8
#define KK 12
#define NPOS 11
#define TBL 4096           // 1 << KK
#define TBLW (TBL / 32)    // 128 words per head

typedef unsigned short u16;
typedef unsigned int u32;

// ws layout (ints):
//   A16 : ushort[S*8]   -> 8192 ints
//   AK16: ushort[S*8]
//   P16 : ushort[S*8]
//   bits: u32[H*TBLW]

__global__ __launch_bounds__(256) void precompute_kernel(
    const int* __restrict__ tokens,        // (S,B) values {0,1}
    const int* __restrict__ conn_heads,    // (H,K)
    const float* __restrict__ head_table,  // (H,4096) values {0.0,1.0}
    u16* __restrict__ A16, u16* __restrict__ AK16, u16* __restrict__ P16,
    u32* __restrict__ bits)
{
    int gid = blockIdx.x * blockDim.x + threadIdx.x;
    if (gid < SS * HH) {
        int s = gid >> 3;
        int h = gid & 7;
        int aq = 0, ak = 0, ap = 0;
        #pragma unroll
        for (int k = 0; k < KK; ++k) {
            int c = conn_heads[h * KK + k];
            int sh = KK - 1 - k;
            if (c < BB) {
                aq |= (tokens[s * BB + c] & 1) << sh;
            } else if (c < 2 * BB) {
                ak |= (tokens[s * BB + (c - BB)] & 1) << sh;
            } else {
                int cp = c - 2 * BB;              // in [0, NPOS)
                ap |= ((s >> (NPOS - 1 - cp)) & 1) << sh;
            }
        }
        A16[gid]  = (u16)aq;
        AK16[gid] = (u16)ak;
        P16[gid]  = (u16)ap;
    } else {
        int w = gid - SS * HH;
        if (w < HH * TBLW) {
            int h = w >> 7;
            int wi = w & (TBLW - 1);
            u32 bv = 0;
            #pragma unroll
            for (int b = 0; b < 32; ++b) {
                if (head_table[h * TBL + wi * 32 + b] > 0.5f) bv |= (1u << b);
            }
            bits[w] = bv;
        }
    }
}

// two packed 12-bit addrs per 32-bit word; heads (2w, 2w+1)
__device__ __forceinline__ int votes_packed(const u32* sbits,
                                            const uint4& q, const uint4& kk, const uint4& pp)
{
    int v = 0;
    u32 w, a0, a1;
    w = q.x | kk.x | pp.x;
    a0 = w & 0xFFFFu; a1 = w >> 16;
    v += (sbits[0 * TBLW + (a0 >> 5)] >> (a0 & 31)) & 1;
    v += (sbits[1 * TBLW + (a1 >> 5)] >> (a1 & 31)) & 1;
    w = q.y | kk.y | pp.y;
    a0 = w & 0xFFFFu; a1 = w >> 16;
    v += (sbits[2 * TBLW + (a0 >> 5)] >> (a0 & 31)) & 1;
    v += (sbits[3 * TBLW + (a1 >> 5)] >> (a1 & 31)) & 1;
    w = q.z | kk.z | pp.z;
    a0 = w & 0xFFFFu; a1 = w >> 16;
    v += (sbits[4 * TBLW + (a0 >> 5)] >> (a0 & 31)) & 1;
    v += (sbits[5 * TBLW + (a1 >> 5)] >> (a1 & 31)) & 1;
    w = q.w | kk.w | pp.w;
    a0 = w & 0xFFFFu; a1 = w >> 16;
    v += (sbits[6 * TBLW + (a0 >> 5)] >> (a0 & 31)) & 1;
    v += (sbits[7 * TBLW + (a1 >> 5)] >> (a1 & 31)) & 1;
    return v;
}

__global__ __launch_bounds__(256) void vote_kernel(
    const u16* __restrict__ A16, const u16* __restrict__ AK16, const u16* __restrict__ P16,
    const u32* __restrict__ bits_g,
    const int* __restrict__ tokens,     // (S,B)
    const int* __restrict__ conn_v,     // (B,K)
    const float* __restrict__ table_v,  // (B,4096)
    float* __restrict__ out)            // (S,B) fp32
{
    __shared__ u32 sbits[HH * TBLW];   // 4 KB
    __shared__ u32 skey[2][4];
    __shared__ int sdone[2];

    const int tid = threadIdx.x;
    const int b = blockIdx.x;
    const int i0 = b;             // short row (i0 <= 1023)
    const int i1 = SS - 1 - b;    // long row  (i1 >= 1024)

    // stage packed tables: 256 threads x 16B = 4 KB exactly
    ((uint4*)sbits)[tid] = ((const uint4*)bits_g)[tid];
    if (tid == 0) { sdone[0] = 0; sdone[1] = 0; }
    __syncthreads();

    const uint4 q0 = *(const uint4*)(A16 + i0 * HH);
    const uint4 q1 = *(const uint4*)(A16 + i1 * HH);

    // key = (v << 12) | (4095 - j): max key == max v, tie -> smallest j.
    // key 0 == "nothing visited"; any visited column yields key >= 2048.
    u32 key0 = 0u, key1 = 0u;
    int done0 = 0, done1 = 0;
    const int nc0 = (i0 >> 8) + 1;   // chunks of 256 for row0
    const int nc1 = (i1 >> 8) + 1;

    for (int c = 0; ; ++c) {
        const int j = (c << 8) + tid;
        int f0 = 0, f1 = 0;
        if (!done0 && j <= i0) {
            const uint4 kk = *(const uint4*)(AK16 + j * HH);
            const uint4 pp = *(const uint4*)(P16 + (i0 - j) * HH);
            int v = votes_packed(sbits, q0, kk, pp);
            u32 key = ((u32)v << 12) | (u32)(4095 - j);
            key0 = key0 > key ? key0 : key;
            f0 = (v == HH);
        }
        if (!done1 && j <= i1) {
            const uint4 kk = *(const uint4*)(AK16 + j * HH);
            const uint4 pp = *(const uint4*)(P16 + (i1 - j) * HH);
            int v = votes_packed(sbits, q1, kk, pp);
            u32 key = ((u32)v << 12) | (u32)(4095 - j);
            key1 = key1 > key ? key1 : key;
            f1 = (v == HH);
        }
        if (f0) sdone[0] = 1;
        if (f1) sdone[1] = 1;
        __syncthreads();
        const int d0 = sdone[0], d1 = sdone[1];
        __syncthreads();   // reads complete before next chunk's flag writes
        done0 = d0 | ((c + 1) >= nc0);
        done1 = d1 | ((c + 1) >= nc1);
        if (done0 && done1) break;
    }

    // 64-lane butterfly max for both rows (no barriers)
    #pragma unroll
    for (int off = 32; off > 0; off >>= 1) {
        u32 o0 = (u32)__shfl_xor((int)key0, off, 64);
        u32 o1 = (u32)__shfl_xor((int)key1, off, 64);
        key0 = key0 > o0 ? key0 : o0;
        key1 = key1 > o1 ? key1 : o1;
    }
    if ((tid & 63) == 0) {
        skey[0][tid >> 6] = key0;
        skey[1][tid >> 6] = key1;
    }
    __syncthreads();

    // threads 0..63 emit row i0, threads 64..127 emit row i1
    if (tid < 128) {
        const int r = tid >> 6;
        const int lane = tid & 63;
        u32 ka = skey[r][0] > skey[r][1] ? skey[r][0] : skey[r][1];
        u32 kb = skey[r][2] > skey[r][3] ? skey[r][2] : skey[r][3];
        u32 kf = ka > kb ? ka : kb;
        const int row = r ? i1 : i0;
        float o = 0.0f;
        if ((kf >> 12) > 0) {
            const int best = 4095 - (int)(kf & 4095u);
            int av = 0;
            #pragma unroll
            for (int k = 0; k < KK; ++k) {
                int c = conn_v[lane * KK + k];
                av |= (tokens[best * BB + c] & 1) << (KK - 1 - k);
            }
            o = table_v[lane * TBL + av];
        }
        out[row * BB + lane] = o;
    }
}

extern "C" void kernel_launch(void* const* d_in, const int* in_sizes, int n_in,
                              void* d_out, int out_size, void* d_ws, size_t ws_size,
                              hipStream_t stream) {
    const int*   tokens     = (const int*)d_in[0];
    const int*   conn_heads = (const int*)d_in[1];
    const float* head_table = (const float*)d_in[2];
    const int*   conn_v     = (const int*)d_in[3];
    const float* table_v    = (const float*)d_in[4];
    float* out = (float*)d_out;

    int* ws = (int*)d_ws;
    u16* A16  = (u16*)ws;                         // S*8 ushorts = 8192 ints
    u16* AK16 = (u16*)(ws + 1 * SS * HH / 2);
    u16* P16  = (u16*)(ws + 2 * SS * HH / 2);
    u32* bits = (u32*)(ws + 3 * SS * HH / 2);

    const int total1 = SS * HH + HH * TBLW;   // 16384 + 1024
    precompute_kernel<<<(total1 + 255) / 256, 256, 0, stream>>>(
        tokens, conn_heads, head_table, A16, AK16, P16, bits);
    vote_kernel<<<SS / 2, 256, 0, stream>>>(
        A16, AK16, P16, bits, tokens, conn_v, table_v, out);
}